// Round 1
// baseline (1388.363 us; speedup 1.0000x reference)
//
#include <hip/hip_runtime.h>

// Globally_Attentive: 512 independent (S=256, N=256) pre-LN attention blocks.
// Fully fused single kernel per (b,k); bf16 MFMA 16x16x32 throughout.
//
// MFMA fragment conventions assumed (gfx950 v_mfma_f32_16x16x32_bf16):
//   A-frag : lane l holds A[l&15][8*(l>>4)+j], j=0..7 (contiguous k)  [inferred]
//   B-frag : lane l holds B[8*(l>>4)+j][l&15]                          [inferred]
//   C/D    : lane l reg r holds D[4*(l>>4)+r][l&15]                    [measured m89]
// Identity: an A-frag of M fed as the B operand is interpreted as M^T.

using short8  = __attribute__((ext_vector_type(8))) short;
using floatx4 = __attribute__((ext_vector_type(4))) float;

#define KSX 32768   // n-stride in x (K*S)

__device__ __forceinline__ ushort f2bf(float f) {
    uint u = __float_as_uint(f);
    u += 0x7fffu + ((u >> 16) & 1u);   // RNE
    return (ushort)(u >> 16);
}
__device__ __forceinline__ float bf2f(ushort h) {
    return __uint_as_float(((uint)h) << 16);
}

// ---------------------------------------------------------------------------
// prep: PE table transposed [n][s] (fp32) + weights packed as bf16 B-fragments
// wpack layout per weight: frag fr = mc*16+nt ; flat = (fr*64 + lane)*8 + j
//   value = w[(lane&15)+16*nt][8*(lane>>4)+j+32*mc]
// ---------------------------------------------------------------------------
__global__ __launch_bounds__(256) void prep_kernel(
    const float* __restrict__ qw, const float* __restrict__ kw,
    const float* __restrict__ vw,
    float* __restrict__ pe, ushort* __restrict__ wpack)
{
    int tid = blockIdx.x * 256 + threadIdx.x;
    if (tid < 65536) {
        int n = tid >> 8, s = tid & 255;
        float d = expf(-0.03597789207803196f * (float)(n & ~1)); // ln(1e4)/256
        float a = d * (float)s;
        pe[tid] = (n & 1) ? cosf(a) : sinf(a);
    } else {
        int id = tid - 65536;
        int wsel = id >> 16;
        int e = id & 65535;
        const float* w = (wsel == 0) ? qw : ((wsel == 1) ? kw : vw);
        int j    = e & 7;
        int lane = (e >> 3) & 63;
        int fr   = e >> 9;
        int nt   = fr & 15;
        int mc   = fr >> 4;
        int row  = (lane & 15) + 16 * nt;          // output-channel n
        int col  = 8 * (lane >> 4) + j + 32 * mc;  // input-channel m
        wpack[wsel * 65536 + e] = f2bf(w[row * 256 + col]);
    }
}

// ---------------------------------------------------------------------------
// main fused kernel: one workgroup (8 waves) per (b,k) slice
// ---------------------------------------------------------------------------
__global__ __launch_bounds__(512, 2) void attn_kernel(
    const float* __restrict__ x,
    const float* __restrict__ ln1w, const float* __restrict__ ln1b,
    const float* __restrict__ qbias, const float* __restrict__ kbias,
    const float* __restrict__ vbias,
    const float* __restrict__ ln2w, const float* __restrict__ ln2b,
    const float* __restrict__ pe, const ushort* __restrict__ wpack,
    float* __restrict__ out)
{
    __shared__ ushort ldsA[128 * 256];   // 64KB: K half1 [kk][n] -> later V^T half1 [n][kk]
    __shared__ ushort ldsB[128 * 256];   // 64KB: K half2           -> later V^T half2
    __shared__ ushort bounce[8 * 512];   // 1KB/wave D->A layout bounce
    __shared__ float  smallbuf[1792];    // w1,b1,w2,b2,qb,kb,vb
    __shared__ float  stats[512];        // per-row (mu1, rstd1)

    const int tid = threadIdx.x;
    const int wid = tid >> 6;
    const int l   = tid & 63;
    const int c   = l & 15;
    const int g   = l >> 4;

    const int bk   = blockIdx.x;
    const int base = (bk >> 7) * (256 * KSX) + (bk & 127) * 256;
    const float* xb = x + base;
    float* ob = out + base;

    const short8* wq8 = (const short8*)(wpack);
    const short8* wk8 = (const short8*)(wpack + 65536);
    const short8* wv8 = (const short8*)(wpack + 131072);

    // ---- P0: stage channel vectors ----
    {
        int i = tid;
        smallbuf[i] = (i < 256) ? ln1w[i] : ln1b[i - 256];
        i = tid + 512;
        smallbuf[i] = (i < 768) ? ln2w[i - 512] : ln2b[i - 768];
        i = tid + 1024;
        smallbuf[i] = (i < 1280) ? qbias[i - 1024] : kbias[i - 1280];
        if (tid < 256) smallbuf[tid + 1536] = vbias[tid];
    }
    __syncthreads();

    ushort* bnc = bounce + (wid << 9);

    // ---- P1: build H (LN1 + PE) into A-fragments; wave owns rows {16w..}+{128+16w..}
    short8 Hfrag[2][8];
    #pragma unroll
    for (int t = 0; t < 2; ++t) {
        const int s = 16 * wid + 128 * t + c;
        float sum = 0.f, ssq = 0.f;
        #pragma unroll
        for (int mc = 0; mc < 8; ++mc) {
            short8 hp;
            #pragma unroll
            for (int j = 0; j < 8; ++j) {
                int m = 32 * mc + 8 * g + j;
                float v = xb[m * KSX + s];
                ushort hb = f2bf(v);
                hp[j] = (short)hb;
                float vb = bf2f(hb);
                sum += vb; ssq += vb * vb;
            }
            Hfrag[t][mc] = hp;
        }
        sum += __shfl_xor(sum, 16); ssq += __shfl_xor(ssq, 16);
        sum += __shfl_xor(sum, 32); ssq += __shfl_xor(ssq, 32);
        float mu   = sum * (1.f / 256.f);
        float var  = ssq * (1.f / 256.f) - mu * mu;
        float rstd = rsqrtf(var + 1e-5f);
        #pragma unroll
        for (int mc = 0; mc < 8; ++mc) {
            short8 hp = Hfrag[t][mc];
            #pragma unroll
            for (int j = 0; j < 8; ++j) {
                int m = 32 * mc + 8 * g + j;
                float v = bf2f((ushort)hp[j]);
                float h = (v - mu) * rstd * smallbuf[m] + smallbuf[256 + m]
                          + pe[m * 256 + s];
                hp[j] = (short)f2bf(h);
            }
            Hfrag[t][mc] = hp;
        }
        if (g == 0) { stats[2 * s] = mu; stats[2 * s + 1] = rstd; }
    }

    // ---- P2: Q = H @ wq^T + qb ; bounce D-layout -> A-fragments (wave-private)
    short8 Qfrag[2][8];
    #pragma unroll
    for (int t = 0; t < 2; ++t) {
        #pragma unroll
        for (int nc = 0; nc < 8; ++nc) {
            floatx4 acc0 = {0.f, 0.f, 0.f, 0.f};
            floatx4 acc1 = {0.f, 0.f, 0.f, 0.f};
            #pragma unroll
            for (int mc = 0; mc < 8; ++mc) {
                short8 a  = Hfrag[t][mc];
                short8 b0 = wq8[(mc * 16 + 2 * nc) * 64 + l];
                short8 b1 = wq8[(mc * 16 + 2 * nc + 1) * 64 + l];
                acc0 = __builtin_amdgcn_mfma_f32_16x16x32_bf16(a, b0, acc0, 0, 0, 0);
                acc1 = __builtin_amdgcn_mfma_f32_16x16x32_bf16(a, b1, acc1, 0, 0, 0);
            }
            #pragma unroll
            for (int e = 0; e < 2; ++e) {
                floatx4 acc = e ? acc1 : acc0;
                float bias = smallbuf[1024 + 16 * (2 * nc + e) + c];
                #pragma unroll
                for (int r = 0; r < 4; ++r) {
                    int row = 4 * g + r;
                    int col = 16 * e + c;
                    bnc[row * 32 + (col ^ ((row & 3) << 3))] = f2bf(acc[r] + bias);
                }
            }
            Qfrag[t][nc] = *(const short8*)&bnc[c * 32 + ((8 * g) ^ ((c & 3) << 3))];
        }
    }

    // ---- P3: K = H @ wk^T + kb, both halves into LDS [kk][n] swizzled
    #pragma unroll
    for (int hf = 0; hf < 2; ++hf) {
        ushort* reg = hf ? ldsB : ldsA;
        #pragma unroll
        for (int nt = 0; nt < 16; ++nt) {
            floatx4 acc = {0.f, 0.f, 0.f, 0.f};
            #pragma unroll
            for (int mc = 0; mc < 8; ++mc)
                acc = __builtin_amdgcn_mfma_f32_16x16x32_bf16(
                    Hfrag[hf][mc], wk8[(mc * 16 + nt) * 64 + l], acc, 0, 0, 0);
            int n = 16 * nt + c;
            float bias = smallbuf[1280 + n];
            #pragma unroll
            for (int r = 0; r < 4; ++r) {
                int kkl = 16 * wid + 4 * g + r;
                reg[kkl * 256 + (n ^ ((kkl & 7) << 3))] = f2bf(acc[r] + bias);
            }
        }
    }
    __syncthreads();

    // ---- P4: S = Q @ K^T (full 32x256 per wave, packed bf16) + rowmax
    uint  Spack[2][4][8];
    float mloc[8];
    #pragma unroll
    for (int i = 0; i < 8; ++i) mloc[i] = -3.0e38f;

    #pragma unroll
    for (int ct = 0; ct < 16; ++ct) {
        const ushort* reg = (ct < 8) ? ldsA : ldsB;
        int kt = ct & 7;
        short8 bfr[8];
        #pragma unroll
        for (int mt = 0; mt < 8; ++mt) {
            int kkl = c + 16 * kt;
            int n0  = 32 * mt + 8 * g;
            bfr[mt] = *(const short8*)&reg[kkl * 256 + (n0 ^ ((kkl & 7) << 3))];
        }
        #pragma unroll
        for (int t = 0; t < 2; ++t) {
            floatx4 acc = {0.f, 0.f, 0.f, 0.f};
            #pragma unroll
            for (int mt = 0; mt < 8; ++mt)
                acc = __builtin_amdgcn_mfma_f32_16x16x32_bf16(
                    Qfrag[t][mt], bfr[mt], acc, 0, 0, 0);
            #pragma unroll
            for (int r = 0; r < 4; ++r) {
                float v = acc[r];
                mloc[t * 4 + r] = fmaxf(mloc[t * 4 + r], v);
                ushort hb = f2bf(v);
                if (ct & 1)
                    Spack[t][r][ct >> 1] = (Spack[t][r][ct >> 1] & 0xffffu) | ((uint)hb << 16);
                else
                    Spack[t][r][ct >> 1] = hb;
            }
        }
    }

    // ---- softmax (full row, no online rescale) ----
    #pragma unroll
    for (int i = 0; i < 8; ++i) {
        mloc[i] = fmaxf(mloc[i], __shfl_xor(mloc[i], 1));
        mloc[i] = fmaxf(mloc[i], __shfl_xor(mloc[i], 2));
        mloc[i] = fmaxf(mloc[i], __shfl_xor(mloc[i], 4));
        mloc[i] = fmaxf(mloc[i], __shfl_xor(mloc[i], 8));
    }
    float lsum[8];
    #pragma unroll
    for (int i = 0; i < 8; ++i) lsum[i] = 0.f;
    #pragma unroll
    for (int t = 0; t < 2; ++t) {
        #pragma unroll
        for (int r = 0; r < 4; ++r) {
            float m = mloc[t * 4 + r];
            #pragma unroll
            for (int d0 = 0; d0 < 8; ++d0) {
                uint d = Spack[t][r][d0];
                float e0 = __expf(bf2f((ushort)(d & 0xffffu)) - m);
                float e1 = __expf(bf2f((ushort)(d >> 16)) - m);
                lsum[t * 4 + r] += e0 + e1;
                Spack[t][r][d0] = (uint)f2bf(e0) | ((uint)f2bf(e1) << 16);
            }
        }
    }
    #pragma unroll
    for (int i = 0; i < 8; ++i) {
        lsum[i] += __shfl_xor(lsum[i], 1);
        lsum[i] += __shfl_xor(lsum[i], 2);
        lsum[i] += __shfl_xor(lsum[i], 4);
        lsum[i] += __shfl_xor(lsum[i], 8);
    }

    // ---- P normalize (* scale/l) + bounce to A-fragments (wave-private) ----
    short8 Pfrag[2][8];
    #pragma unroll
    for (int t = 0; t < 2; ++t) {
        #pragma unroll
        for (int kc = 0; kc < 8; ++kc) {
            #pragma unroll
            for (int r = 0; r < 4; ++r) {
                float f = 0.0625f / lsum[t * 4 + r];   // scale = 1/sqrt(256)
                uint d = Spack[t][r][kc];
                int row = 4 * g + r;
                bnc[row * 32 + (c        ^ ((row & 3) << 3))] = f2bf(bf2f((ushort)(d & 0xffffu)) * f);
                bnc[row * 32 + ((16 + c) ^ ((row & 3) << 3))] = f2bf(bf2f((ushort)(d >> 16)) * f);
            }
            Pfrag[t][kc] = *(const short8*)&bnc[c * 32 + ((8 * g) ^ ((c & 3) << 3))];
        }
    }
    __syncthreads();   // all S reads of ldsA/ldsB done before V overwrites

    // ---- P7: V = H @ wv^T + vb, stored transposed [n][kk] swizzled ----
    #pragma unroll
    for (int hf = 0; hf < 2; ++hf) {
        ushort* reg = hf ? ldsB : ldsA;
        #pragma unroll
        for (int nt = 0; nt < 16; ++nt) {
            floatx4 acc = {0.f, 0.f, 0.f, 0.f};
            #pragma unroll
            for (int mc = 0; mc < 8; ++mc)
                acc = __builtin_amdgcn_mfma_f32_16x16x32_bf16(
                    Hfrag[hf][mc], wv8[(mc * 16 + nt) * 64 + l], acc, 0, 0, 0);
            int n = 16 * nt + c;
            float bias = smallbuf[1536 + n];
            #pragma unroll
            for (int r = 0; r < 4; ++r) {
                int kkl = 16 * wid + 4 * g + r;
                reg[n * 128 + (kkl ^ ((n & 7) << 3))] = f2bf(acc[r] + bias);
            }
        }
    }
    __syncthreads();

    // ---- P10: O^T = V^T @ P^T  (D rows = n, cols = q) ----
    floatx4 O[2][16];
    #pragma unroll
    for (int t = 0; t < 2; ++t)
        #pragma unroll
        for (int nt = 0; nt < 16; ++nt) {
            floatx4 z = {0.f, 0.f, 0.f, 0.f};
            O[t][nt] = z;
        }
    #pragma unroll
    for (int kc = 0; kc < 8; ++kc) {
        const ushort* reg = (kc < 4) ? ldsA : ldsB;
        int kc4 = kc & 3;
        #pragma unroll
        for (int nt = 0; nt < 16; ++nt) {
            int n  = c + 16 * nt;
            int k0 = 8 * g + 32 * kc4;
            short8 a = *(const short8*)&reg[n * 128 + (k0 ^ ((n & 7) << 3))];
            O[0][nt] = __builtin_amdgcn_mfma_f32_16x16x32_bf16(a, Pfrag[0][kc], O[0][nt], 0, 0, 0);
            O[1][nt] = __builtin_amdgcn_mfma_f32_16x16x32_bf16(a, Pfrag[1][kc], O[1][nt], 0, 0, 0);
        }
    }

    // ---- epilogue: res recompute + LN2 + (+x) + store, all in registers ----
    #pragma unroll
    for (int t = 0; t < 2; ++t) {
        const int q = 16 * wid + 128 * t + c;
        float mu1 = stats[2 * q], rstd1 = stats[2 * q + 1];
        float s1 = 0.f, s2 = 0.f;
        #pragma unroll
        for (int nt = 0; nt < 16; ++nt) {
            floatx4 o = O[t][nt];
            #pragma unroll
            for (int r = 0; r < 4; ++r) {
                int n = 16 * nt + 4 * g + r;
                float xv  = xb[n * KSX + q];
                float res = (xv - mu1) * rstd1 * smallbuf[n] + smallbuf[256 + n]
                            + pe[n * 256 + q];
                float h2 = res + o[r];
                o[r] = h2;
                s1 += h2; s2 += h2 * h2;
            }
            O[t][nt] = o;
        }
        s1 += __shfl_xor(s1, 16); s2 += __shfl_xor(s2, 16);
        s1 += __shfl_xor(s1, 32); s2 += __shfl_xor(s2, 32);
        float mu2   = s1 * (1.f / 256.f);
        float var2  = s2 * (1.f / 256.f) - mu2 * mu2;
        float rstd2 = rsqrtf(var2 + 1e-5f);
        #pragma unroll
        for (int nt = 0; nt < 16; ++nt) {
            floatx4 o = O[t][nt];
            #pragma unroll
            for (int r = 0; r < 4; ++r) {
                int n = 16 * nt + 4 * g + r;
                float xv = xb[n * KSX + q];
                float y  = (o[r] - mu2) * rstd2 * smallbuf[512 + n]
                           + smallbuf[768 + n] + xv;
                ob[n * KSX + q] = y;
            }
        }
    }
}

// ---------------------------------------------------------------------------
extern "C" void kernel_launch(void* const* d_in, const int* in_sizes, int n_in,
                              void* d_out, int out_size, void* d_ws, size_t ws_size,
                              hipStream_t stream)
{
    (void)in_sizes; (void)n_in; (void)out_size; (void)ws_size;
    const float* x    = (const float*)d_in[0];
    const float* ln1w = (const float*)d_in[1];
    const float* ln1b = (const float*)d_in[2];
    const float* qw   = (const float*)d_in[3];
    const float* qb   = (const float*)d_in[4];
    const float* kw   = (const float*)d_in[5];
    const float* kb   = (const float*)d_in[6];
    const float* vw   = (const float*)d_in[7];
    const float* vb   = (const float*)d_in[8];
    const float* ln2w = (const float*)d_in[9];
    const float* ln2b = (const float*)d_in[10];
    float* out = (float*)d_out;

    float*  pe    = (float*)d_ws;                       // 256*256 f32 = 256KB
    ushort* wpack = (ushort*)((char*)d_ws + 262144);    // 3 * 65536 bf16 = 384KB

    prep_kernel<<<1024, 256, 0, stream>>>(qw, kw, vw, pe, wpack);
    attn_kernel<<<512, 512, 0, stream>>>(x, ln1w, ln1b, qb, kb, vb,
                                         ln2w, ln2b, pe, wpack, out);
}